// Round 1
// baseline (210.792 us; speedup 1.0000x reference)
//
#include <hip/hip_runtime.h>

// Problem constants (fixed by the reference harness).
#define BB 64
#define SS 2048
#define DD 256
#define NSPLIT 32
#define S_PER (SS / NSPLIT)  // 64 rows of S per partial block

// ---------------------------------------------------------------------------
// Kernel A: per-doc sum of idf weights (normalizer for the weighted mean).
// ---------------------------------------------------------------------------
__global__ __launch_bounds__(256) void wsum_kernel(
    const int* __restrict__ chunk, const float* __restrict__ idf,
    float* __restrict__ wsum) {
  int b = blockIdx.x;
  int tid = threadIdx.x;
  float s = 0.f;
  for (int i = tid; i < SS; i += 256) s += idf[chunk[b * SS + i]];
  __shared__ float red[256];
  red[tid] = s;
  __syncthreads();
  for (int off = 128; off > 0; off >>= 1) {
    if (tid < off) red[tid] += red[tid + off];
    __syncthreads();
  }
  if (tid == 0) wsum[b] = red[0];
}

// ---------------------------------------------------------------------------
// Kernel B: single pass over encoding. Block = (split, b). Each thread owns a
// float4 slice of D and accumulates 5 stats over 16 s-rows in registers.
// Lane layout: dg = tid&63 picks the float4 column -> each wave's load is one
// contiguous 1 KiB row (16 B/lane). ssub = tid>>6 staggers the 4 waves across
// s-rows; cross-wave combine happens once in LDS at the end.
// ---------------------------------------------------------------------------
__global__ __launch_bounds__(256) void partial_kernel(
    const int* __restrict__ chunk, const float* __restrict__ enc,
    const float* __restrict__ idf, float* __restrict__ pswe,
    float* __restrict__ pse, float* __restrict__ pse2,
    float* __restrict__ pmx, float* __restrict__ pmn) {
  int split = blockIdx.x;
  int b = blockIdx.y;
  int tid = threadIdx.x;
  int dg = tid & 63;
  int ssub = tid >> 6;
  int s0 = split * S_PER;

  // Stage this block's 64 idf weights into LDS (one gather per row).
  __shared__ float sw[S_PER];
  if (tid < S_PER) sw[tid] = idf[chunk[b * SS + s0 + tid]];
  __syncthreads();

  float swe[4] = {0.f, 0.f, 0.f, 0.f};
  float se[4] = {0.f, 0.f, 0.f, 0.f};
  float se2[4] = {0.f, 0.f, 0.f, 0.f};
  float mx[4], mn[4];
#pragma unroll
  for (int k = 0; k < 4; k++) {
    mx[k] = -3.4028234e38f;
    mn[k] = 3.4028234e38f;
  }

  const float* base = enc + ((size_t)(b * SS + s0)) * DD + (size_t)dg * 4;
#pragma unroll 4
  for (int i = 0; i < S_PER / 4; i++) {
    int srel = ssub + 4 * i;  // wave-uniform
    float w = sw[srel];       // LDS broadcast (free)
    float4 e = *(const float4*)(base + (size_t)srel * DD);
    float ev[4] = {e.x, e.y, e.z, e.w};
#pragma unroll
    for (int k = 0; k < 4; k++) {
      swe[k] = fmaf(w, ev[k], swe[k]);
      se[k] += ev[k];
      se2[k] = fmaf(ev[k], ev[k], se2[k]);
      mx[k] = fmaxf(mx[k], ev[k]);
      mn[k] = fminf(mn[k], ev[k]);
    }
  }

  // Cross-wave (ssub) combine in LDS: 5 stats x 4 waves x 256 d = 20 KiB.
  __shared__ float red[5][4][DD];
#pragma unroll
  for (int k = 0; k < 4; k++) {
    red[0][ssub][dg * 4 + k] = swe[k];
    red[1][ssub][dg * 4 + k] = se[k];
    red[2][ssub][dg * 4 + k] = se2[k];
    red[3][ssub][dg * 4 + k] = mx[k];
    red[4][ssub][dg * 4 + k] = mn[k];
  }
  __syncthreads();

  int d = tid;  // one output column per thread, coalesced stores
  size_t gbase = ((size_t)b * NSPLIT + split) * DD + d;
  pswe[gbase] = (red[0][0][d] + red[0][1][d]) + (red[0][2][d] + red[0][3][d]);
  pse[gbase] = (red[1][0][d] + red[1][1][d]) + (red[1][2][d] + red[1][3][d]);
  pse2[gbase] = (red[2][0][d] + red[2][1][d]) + (red[2][2][d] + red[2][3][d]);
  pmx[gbase] = fmaxf(fmaxf(red[3][0][d], red[3][1][d]),
                     fmaxf(red[3][2][d], red[3][3][d]));
  pmn[gbase] = fminf(fminf(red[4][0][d], red[4][1][d]),
                     fminf(red[4][2][d], red[4][3][d]));
}

// ---------------------------------------------------------------------------
// Kernel C: combine the 32 split-partials per (b, d) and write the 4 outputs.
// ---------------------------------------------------------------------------
__global__ __launch_bounds__(256) void final_kernel(
    const float* __restrict__ pswe, const float* __restrict__ pse,
    const float* __restrict__ pse2, const float* __restrict__ pmx,
    const float* __restrict__ pmn, const float* __restrict__ wsum,
    float* __restrict__ out) {
  int b = blockIdx.x;
  int d = threadIdx.x;
  float swe = 0.f, se = 0.f, se2 = 0.f;
  float mx = -3.4028234e38f, mn = 3.4028234e38f;
  for (int sp = 0; sp < NSPLIT; sp++) {
    size_t idx = ((size_t)b * NSPLIT + sp) * DD + d;
    swe += pswe[idx];
    se += pse[idx];
    se2 += pse2[idx];
    mx = fmaxf(mx, pmx[idx]);
    mn = fminf(mn, pmn[idx]);
  }
  float mean_w = swe / wsum[b];
  float mu = se / (float)SS;
  float var = (se2 - (float)SS * mu * mu) / (float)(SS - 1);
  float stdv = sqrtf(fmaxf(var, 0.f));
  size_t ob = (size_t)b * 4 * DD;
  out[ob + d] = mean_w;
  out[ob + DD + d] = mx;
  out[ob + 2 * DD + d] = mn;
  out[ob + 3 * DD + d] = stdv;
}

extern "C" void kernel_launch(void* const* d_in, const int* in_sizes, int n_in,
                              void* d_out, int out_size, void* d_ws,
                              size_t ws_size, hipStream_t stream) {
  const int* chunk = (const int*)d_in[0];
  const float* enc = (const float*)d_in[1];
  const float* idf = (const float*)d_in[2];
  float* out = (float*)d_out;

  float* ws = (float*)d_ws;
  size_t n = (size_t)BB * NSPLIT * DD;  // 524288 floats per stat array
  float* pswe = ws;
  float* pse = ws + n;
  float* pse2 = ws + 2 * n;
  float* pmx = ws + 3 * n;
  float* pmn = ws + 4 * n;
  float* wsum = ws + 5 * n;  // 64 floats

  wsum_kernel<<<BB, 256, 0, stream>>>(chunk, idf, wsum);
  partial_kernel<<<dim3(NSPLIT, BB), 256, 0, stream>>>(chunk, enc, idf, pswe,
                                                       pse, pse2, pmx, pmn);
  final_kernel<<<BB, DD, 0, stream>>>(pswe, pse, pse2, pmx, pmn, wsum, out);
}

// Round 2
// 201.669 us; speedup vs baseline: 1.0452x; 1.0452x over previous
//
#include <hip/hip_runtime.h>

// Problem constants (fixed by the reference harness).
#define BB 64
#define SS 2048
#define DD 256
#define NSPLIT 32
#define S_PER (SS / NSPLIT)  // 64 rows of S per partial block

#define FLT_BIG 3.4028234e38f

// ---------------------------------------------------------------------------
// Kernel 1: single pass over encoding. Block = (split, b). Each thread owns a
// float4 slice of D and accumulates 5 stats over 16 s-rows in registers.
// Lane layout: dg = tid&63 picks the float4 column -> each wave's load is one
// contiguous 1 KiB row (= exactly one D-row, 16 B/lane coalescing optimum).
// ssub = tid>>6 staggers the 4 waves across s-rows; cross-wave combine in LDS
// at the end. The per-split idf weight sum (normalizer partial) is computed
// here too via a wave-0 shuffle reduce over the staged weights -> the old
// standalone wsum_kernel dispatch is gone.
// ---------------------------------------------------------------------------
__global__ __launch_bounds__(256) void partial_kernel(
    const int* __restrict__ chunk, const float* __restrict__ enc,
    const float* __restrict__ idf, float* __restrict__ pswe,
    float* __restrict__ pse, float* __restrict__ pse2,
    float* __restrict__ pmx, float* __restrict__ pmn,
    float* __restrict__ pws) {
  int split = blockIdx.x;
  int b = blockIdx.y;
  int tid = threadIdx.x;
  int dg = tid & 63;
  int ssub = tid >> 6;
  int s0 = split * S_PER;

  // Stage this block's 64 idf weights into LDS (one gather per row).
  __shared__ float sw[S_PER];
  if (tid < S_PER) sw[tid] = idf[chunk[b * SS + s0 + tid]];
  __syncthreads();

  // Wave 0: shuffle-reduce the 64 staged weights -> per-split wsum partial.
  if (tid < 64) {
    float w = sw[tid];
#pragma unroll
    for (int off = 32; off > 0; off >>= 1) w += __shfl_down(w, off, 64);
    if (tid == 0) pws[b * NSPLIT + split] = w;
  }

  float swe[4] = {0.f, 0.f, 0.f, 0.f};
  float se[4] = {0.f, 0.f, 0.f, 0.f};
  float se2[4] = {0.f, 0.f, 0.f, 0.f};
  float mx[4], mn[4];
#pragma unroll
  for (int k = 0; k < 4; k++) {
    mx[k] = -FLT_BIG;
    mn[k] = FLT_BIG;
  }

  const float* base = enc + ((size_t)(b * SS + s0)) * DD + (size_t)dg * 4;
#pragma unroll 8
  for (int i = 0; i < S_PER / 4; i++) {
    int srel = ssub + 4 * i;  // wave-uniform
    float w = sw[srel];       // LDS broadcast (free)
    float4 e = *(const float4*)(base + (size_t)srel * DD);
    float ev[4] = {e.x, e.y, e.z, e.w};
#pragma unroll
    for (int k = 0; k < 4; k++) {
      swe[k] = fmaf(w, ev[k], swe[k]);
      se[k] += ev[k];
      se2[k] = fmaf(ev[k], ev[k], se2[k]);
      mx[k] = fmaxf(mx[k], ev[k]);
      mn[k] = fminf(mn[k], ev[k]);
    }
  }

  // Cross-wave (ssub) combine in LDS: 5 stats x 4 waves x 256 d = 20 KiB.
  __shared__ float red[5][4][DD];
#pragma unroll
  for (int k = 0; k < 4; k++) {
    red[0][ssub][dg * 4 + k] = swe[k];
    red[1][ssub][dg * 4 + k] = se[k];
    red[2][ssub][dg * 4 + k] = se2[k];
    red[3][ssub][dg * 4 + k] = mx[k];
    red[4][ssub][dg * 4 + k] = mn[k];
  }
  __syncthreads();

  int d = tid;  // one output column per thread, coalesced stores
  size_t gbase = ((size_t)b * NSPLIT + split) * DD + d;
  pswe[gbase] = (red[0][0][d] + red[0][1][d]) + (red[0][2][d] + red[0][3][d]);
  pse[gbase] = (red[1][0][d] + red[1][1][d]) + (red[1][2][d] + red[1][3][d]);
  pse2[gbase] = (red[2][0][d] + red[2][1][d]) + (red[2][2][d] + red[2][3][d]);
  pmx[gbase] = fmaxf(fmaxf(red[3][0][d], red[3][1][d]),
                     fmaxf(red[3][2][d], red[3][3][d]));
  pmn[gbase] = fminf(fminf(red[4][0][d], red[4][1][d]),
                     fminf(red[4][2][d], red[4][3][d]));
}

// ---------------------------------------------------------------------------
// Kernel 2: combine the 32 split-partials per (b, d) and write the 4 outputs.
// 1024 threads/block: 4 groups x 8 splits each, LDS combine, then each thread
// writes exactly one of the 1024 output elements of doc b (stat = tid>>8).
// ---------------------------------------------------------------------------
__global__ __launch_bounds__(1024) void final_kernel(
    const float* __restrict__ pswe, const float* __restrict__ pse,
    const float* __restrict__ pse2, const float* __restrict__ pmx,
    const float* __restrict__ pmn, const float* __restrict__ pws,
    float* __restrict__ out) {
  int b = blockIdx.x;
  int tid = threadIdx.x;
  int d = tid & 255;
  int grp = tid >> 8;  // 0..3, each handles 8 splits

  float swe = 0.f, se = 0.f, se2 = 0.f;
  float mx = -FLT_BIG, mn = FLT_BIG;
#pragma unroll
  for (int j = 0; j < NSPLIT / 4; j++) {
    int sp = grp * (NSPLIT / 4) + j;
    size_t idx = ((size_t)b * NSPLIT + sp) * DD + d;
    swe += pswe[idx];
    se += pse[idx];
    se2 += pse2[idx];
    mx = fmaxf(mx, pmx[idx]);
    mn = fminf(mn, pmn[idx]);
  }

  __shared__ float red[5][4][DD];
  red[0][grp][d] = swe;
  red[1][grp][d] = se;
  red[2][grp][d] = se2;
  red[3][grp][d] = mx;
  red[4][grp][d] = mn;

  __shared__ float wsp[NSPLIT];
  __shared__ float wtot_s;
  if (tid < NSPLIT) wsp[tid] = pws[b * NSPLIT + tid];
  __syncthreads();
  if (tid == 0) {
    float t = 0.f;
#pragma unroll
    for (int i = 0; i < NSPLIT; i++) t += wsp[i];
    wtot_s = t;
  }
  __syncthreads();

  float cswe = (red[0][0][d] + red[0][1][d]) + (red[0][2][d] + red[0][3][d]);
  float cse = (red[1][0][d] + red[1][1][d]) + (red[1][2][d] + red[1][3][d]);
  float cse2 = (red[2][0][d] + red[2][1][d]) + (red[2][2][d] + red[2][3][d]);
  float cmx = fmaxf(fmaxf(red[3][0][d], red[3][1][d]),
                    fmaxf(red[3][2][d], red[3][3][d]));
  float cmn = fminf(fminf(red[4][0][d], red[4][1][d]),
                    fminf(red[4][2][d], red[4][3][d]));

  int stat = tid >> 8;  // 0:mean 1:max 2:min 3:std
  float val;
  if (stat == 0) {
    val = cswe / wtot_s;
  } else if (stat == 1) {
    val = cmx;
  } else if (stat == 2) {
    val = cmn;
  } else {
    float mu = cse / (float)SS;
    val = sqrtf(fmaxf((cse2 - (float)SS * mu * mu) / (float)(SS - 1), 0.f));
  }
  out[(size_t)b * 4 * DD + tid] = val;
}

extern "C" void kernel_launch(void* const* d_in, const int* in_sizes, int n_in,
                              void* d_out, int out_size, void* d_ws,
                              size_t ws_size, hipStream_t stream) {
  const int* chunk = (const int*)d_in[0];
  const float* enc = (const float*)d_in[1];
  const float* idf = (const float*)d_in[2];
  float* out = (float*)d_out;

  float* ws = (float*)d_ws;
  size_t n = (size_t)BB * NSPLIT * DD;  // 524288 floats per stat array
  float* pswe = ws;
  float* pse = ws + n;
  float* pse2 = ws + 2 * n;
  float* pmx = ws + 3 * n;
  float* pmn = ws + 4 * n;
  float* pws = ws + 5 * n;  // 2048 floats

  partial_kernel<<<dim3(NSPLIT, BB), 256, 0, stream>>>(chunk, enc, idf, pswe,
                                                       pse, pse2, pmx, pmn,
                                                       pws);
  final_kernel<<<BB, 1024, 0, stream>>>(pswe, pse, pse2, pmx, pmn, pws, out);
}